// Round 5
// baseline (1433.108 us; speedup 1.0000x reference)
//
// HNHN layer on MI355X (gfx950). Round 5: barrier-light register-GEMM MM cores.
//   K1:  rowsum -> node_card; B1 -> bf16 b1h[n][e] AND b1hT[e][n] (fp32 LDS transpose)
//   K2:  y0 = x0@W0; epilogue y0sT[c][n] = bf16(node_card[n]*y0[n,c]);  K2b aux rows
//   MM1T: mm1pT[sp][c][e] = y0sT @ b1hT-rows   (M=272, N=8192, K=16384, splitK=8)
//         Y-frags global->VGPR direct (L2-hot, no barrier); stream via dbuf LDS,
//         ONE barrier per 128-k chunk, asyncs a full chunk ahead.
//   K3:  reduce partials, x1 = p/d1sum + b01 -> out1/x1bf; edge_card = colsum^-1.5
//   K5:  y1sT[c][e] = bf16(edge_card[e]*(x1@W1));  K5b aux row
//   MM2T: mm2pT[sp][c][n] = y1sT @ b1h-rows    (M=272, N=16384, K=8192, splitK=4)
//   K6:  reduce partials, out0[n][c] = relu(s/d0sum + b10)
#include <hip/hip_runtime.h>
#include <stdint.h>

#define NN 16384
#define NE 8192
#define CH 256
#define MM1_SPLIT 8
#define MM2_SPLIT 4

typedef __attribute__((ext_vector_type(8))) short bf16x8;
typedef __attribute__((ext_vector_type(4))) float f32x4;

__device__ __forceinline__ unsigned short f2bf(float f) {  // RNE fp32->bf16
  unsigned u = __float_as_uint(f);
  u += 0x7FFFu + ((u >> 16) & 1u);
  return (unsigned short)(u >> 16);
}
__device__ __forceinline__ unsigned pack_trunc2(float a, float b) {  // exact for 0/1
  return (__float_as_uint(b) & 0xFFFF0000u) | (__float_as_uint(a) >> 16);
}
__device__ __forceinline__ void async_copy16(const void* gptr, void* lptr) {
  __builtin_amdgcn_global_load_lds((const __attribute__((address_space(1))) unsigned int*)gptr,
                                   (__attribute__((address_space(3))) unsigned int*)lptr,
                                   16, 0, 0);
}

// ---------------- K0: weight transpose to bf16 ----------------
__global__ void k0_transpose_w(const float* __restrict__ W0, const float* __restrict__ W1,
                               unsigned short* __restrict__ W0T, unsigned short* __restrict__ W1T) {
  const float* W = blockIdx.y ? W1 : W0;
  unsigned short* WT = blockIdx.y ? W1T : W0T;
  int n = blockIdx.x;
  int k = threadIdx.x;
  WT[n * CH + k] = f2bf(W[k * CH + n]);
}

// ---------------- K1: rowsum -> node_card; b1h + b1hT via fp32 LDS transpose -------
__global__ __launch_bounds__(256) void k1_prep(const float* __restrict__ B1,
                                               unsigned short* __restrict__ b1h,
                                               unsigned short* __restrict__ b1hT,
                                               float* __restrict__ node_card) {
  __shared__ float ldsf[64 * 68];
  __shared__ float rsl[64][17];
  const int tid = threadIdx.x;
  const int n0 = blockIdx.x * 64;
  const int r0 = tid >> 4;        // 0..15
  const int c4 = (tid & 15) * 4;  // 0..60
  const int er = tid >> 2;        // 0..63
  const int nq = (tid & 3) * 16;  // 0,16,32,48
  float rsum[4] = {0.f, 0.f, 0.f, 0.f};
  for (int e0 = 0; e0 < NE; e0 += 64) {
    float4 v[4];
#pragma unroll
    for (int p = 0; p < 4; ++p) {
      v[p] = *(const float4*)(B1 + (size_t)(n0 + r0 + 16 * p) * NE + e0 + c4);
      rsum[p] += v[p].x + v[p].y + v[p].z + v[p].w;
      uint2 w;
      w.x = pack_trunc2(v[p].x, v[p].y);
      w.y = pack_trunc2(v[p].z, v[p].w);
      *(uint2*)(b1h + (size_t)(n0 + r0 + 16 * p) * NE + e0 + c4) = w;
    }
    __syncthreads();  // previous iteration's ldsf reads done
#pragma unroll
    for (int p = 0; p < 4; ++p) *(float4*)&ldsf[(r0 + 16 * p) * 68 + c4] = v[p];
    __syncthreads();
    unsigned wv[8];
#pragma unroll
    for (int h = 0; h < 8; ++h) {
      float a = ldsf[(nq + 2 * h) * 68 + er];
      float b = ldsf[(nq + 2 * h + 1) * 68 + er];
      wv[h] = pack_trunc2(a, b);
    }
    uint4* tp = (uint4*)(b1hT + (size_t)(e0 + er) * NN + n0 + nq);
    tp[0] = make_uint4(wv[0], wv[1], wv[2], wv[3]);
    tp[1] = make_uint4(wv[4], wv[5], wv[6], wv[7]);
  }
#pragma unroll
  for (int p = 0; p < 4; ++p) rsl[r0 + 16 * p][tid & 15] = rsum[p];
  __syncthreads();
  if (tid < 64) {
    float s = 0.f;
#pragma unroll
    for (int q = 0; q < 16; ++q) s += rsl[tid][q];
    node_card[n0 + tid] = rsqrtf(s);
  }
}

// ---------------- K2: y0 GEMM + scaled transpose epilogue ----------------
__global__ __launch_bounds__(256) void k2_y0(const float* __restrict__ X0,
                                             const unsigned short* __restrict__ W0T,
                                             const float* __restrict__ node_card,
                                             unsigned short* __restrict__ y0sT) {
  __shared__ unsigned short a_lds[64 * 32];
  __shared__ unsigned short b_lds[256 * 32];
  const int tid = threadIdx.x;
  const int wave = tid >> 6, lane = tid & 63;
  const int quad = lane >> 4, l15 = lane & 15;
  const int m0 = blockIdx.x * 64;
  const int ar = tid >> 3, ac = (tid & 7) * 4;

  f32x4 acc[4][4];
  const f32x4 fz = {0.f, 0.f, 0.f, 0.f};
#pragma unroll
  for (int i = 0; i < 4; ++i)
#pragma unroll
    for (int j = 0; j < 4; ++j) acc[i][j] = fz;

  for (int k0 = 0; k0 < CH; k0 += 32) {
    __syncthreads();
#pragma unroll
    for (int p = 0; p < 2; ++p) {
      float4 v = *(const float4*)(X0 + (size_t)(m0 + ar + p * 32) * CH + k0 + ac);
      uint2 w;
      w.x = ((unsigned)f2bf(v.x)) | ((unsigned)f2bf(v.y) << 16);
      w.y = ((unsigned)f2bf(v.z)) | ((unsigned)f2bf(v.w) << 16);
      *(uint2*)&a_lds[(ar + p * 32) * 32 + ac] = w;
    }
#pragma unroll
    for (int i = 0; i < 4; ++i) {
      int rowbase = wave * 64 + i * 16;
      const unsigned short* g = W0T + (size_t)(rowbase + (lane >> 2)) * CH + k0 + (lane & 3) * 8;
      async_copy16(g, &b_lds[rowbase * 32]);
    }
    __syncthreads();
    bf16x8 af[4];
#pragma unroll
    for (int i = 0; i < 4; ++i)
      af[i] = *(const bf16x8*)&a_lds[(i * 16 + l15) * 32 + quad * 8];
#pragma unroll
    for (int j = 0; j < 4; ++j) {
      bf16x8 bfr = *(const bf16x8*)&b_lds[(wave * 64 + j * 16 + l15) * 32 + quad * 8];
#pragma unroll
      for (int i = 0; i < 4; ++i)
        acc[i][j] = __builtin_amdgcn_mfma_f32_16x16x32_bf16(af[i], bfr, acc[i][j], 0, 0, 0);
    }
  }
#pragma unroll
  for (int i = 0; i < 4; ++i) {
    int row4 = m0 + i * 16 + quad * 4;
    float4 nc = *(const float4*)(node_card + row4);
#pragma unroll
    for (int j = 0; j < 4; ++j) {
      int col = wave * 64 + j * 16 + l15;
      f32x4 v = acc[i][j];
      ushort4 o;
      o.x = f2bf(v[0] * nc.x);
      o.y = f2bf(v[1] * nc.y);
      o.z = f2bf(v[2] * nc.z);
      o.w = f2bf(v[3] * nc.w);
      *(ushort4*)&y0sT[(size_t)col * NN + row4] = o;
    }
  }
}

// ---------------- K2b: y0sT aux rows ----------------
__global__ void k2b_aux(const float* __restrict__ node_card, unsigned short* __restrict__ y0sT) {
  int n = blockIdx.x * 256 + threadIdx.x;
  y0sT[(size_t)256 * NN + n] = f2bf(node_card[n]);
  y0sT[(size_t)257 * NN + n] = 0x3F80;  // 1.0 bf16
#pragma unroll
  for (int r = 258; r < 272; ++r) y0sT[(size_t)r * NN + n] = 0;
}

// ------- MM core v2: outT[sp][272][NSZ] = Y(272 x K) @ Bm(NSZ x K) -------------
// Y-frags: global->VGPR direct per wave (L2-hot; no barrier dependency).
// Stream (Bm rows): double-buffered LDS, asyncs one full 128-k chunk ahead,
// ONE __syncthreads per chunk. Wave w owns m-groups 4w..4w+3 (+16 for w=3).
template <int NSZ, int SPLIT>
__device__ __forceinline__ void mm_core(const unsigned short* __restrict__ Y,
                                        const unsigned short* __restrict__ Bm,
                                        float* __restrict__ outp) {
  constexpr int K = (NSZ == NE) ? NN : NE;
  constexpr int KS = K / SPLIT;
  __shared__ unsigned short b4[2][4][64][32];  // [buf][kstep][row][32k] = 32 KB
  const int tid = threadIdx.x;
  const int wave = tid >> 6, lane = tid & 63;
  const int quad = lane >> 4, l15 = lane & 15;
  const int bid = blockIdx.x;
  const int sp = bid & (SPLIT - 1);  // splitK slice -> XCD (round-robin dispatch)
  const int n0 = (bid / SPLIT) * 64;
  const int kbase = sp * KS;
  const int gm = (wave == 3) ? 5 : 4;

  f32x4 acc[5][4];
  const f32x4 fz = {0.f, 0.f, 0.f, 0.f};
#pragma unroll
  for (int i = 0; i < 5; ++i)
#pragma unroll
    for (int j = 0; j < 4; ++j) acc[i][j] = fz;

  const unsigned short* bp =
      Bm + (size_t)(n0 + wave * 16 + (lane >> 2)) * K + kbase + (lane & 3) * 8;
  const unsigned short* yb = Y + (size_t)(wave * 64 + l15) * K + kbase + quad * 8;

  bf16x8 yf[2][5];

#pragma unroll 1
  for (int pre = 0; pre < 1; ++pre) {  // stage chunk 0
#pragma unroll
    for (int i = 0; i < 4; ++i) async_copy16(bp + i * 32, &b4[0][i][wave * 16][0]);
  }

  for (int kc = 0; kc < KS; kc += 128) {
    const int cb = (kc >> 7) & 1;
    // preload Y-frags for t=0 of this chunk (global, L2) BEFORE the barrier
#pragma unroll
    for (int i = 0; i < 5; ++i)
      if (i < gm) yf[0][i] = *(const bf16x8*)(yb + (size_t)i * 16 * K + kc);
    __syncthreads();  // drains chunk-cb asyncs (issued a full chunk ago)
    if (kc + 128 < KS) {
#pragma unroll
      for (int i = 0; i < 4; ++i)
        async_copy16(bp + kc + 128 + i * 32, &b4[cb ^ 1][i][wave * 16][0]);
    }
#pragma unroll
    for (int t = 0; t < 4; ++t) {
      if (t < 3) {
#pragma unroll
        for (int i = 0; i < 5; ++i)
          if (i < gm)
            yf[(t + 1) & 1][i] = *(const bf16x8*)(yb + (size_t)i * 16 * K + kc + (t + 1) * 32);
      }
      bf16x8 bfr[4];
#pragma unroll
      for (int j = 0; j < 4; ++j)
        bfr[j] = *(const bf16x8*)&b4[cb][t][j * 16 + l15][quad * 8];
#pragma unroll
      for (int j = 0; j < 4; ++j) {
#pragma unroll
        for (int i = 0; i < 5; ++i)
          if (i < gm)
            acc[i][j] = __builtin_amdgcn_mfma_f32_16x16x32_bf16(yf[t & 1][i], bfr[j], acc[i][j], 0, 0, 0);
      }
    }
  }
  float* op = outp + (size_t)sp * 272 * NSZ;
#pragma unroll
  for (int i = 0; i < 5; ++i) {
    if (i < gm) {
      int c0 = (wave * 4 + i) * 16 + quad * 4;
#pragma unroll
      for (int j = 0; j < 4; ++j) {
        int n = n0 + j * 16 + l15;
#pragma unroll
        for (int r = 0; r < 4; ++r) op[(size_t)(c0 + r) * NSZ + n] = acc[i][j][r];
      }
    }
  }
}

__global__ __launch_bounds__(256) void mm1t_kernel(const unsigned short* __restrict__ y0sT,
                                                   const unsigned short* __restrict__ b1hT,
                                                   float* __restrict__ mm1pT) {
  mm_core<NE, MM1_SPLIT>(y0sT, b1hT, mm1pT);
}
__global__ __launch_bounds__(256) void mm2t_kernel(const unsigned short* __restrict__ y1sT,
                                                   const unsigned short* __restrict__ b1h,
                                                   float* __restrict__ mm2pT) {
  mm_core<NN, MM2_SPLIT>(y1sT, b1h, mm2pT);
}

// ---------------- K3: reduce partials + finalize edges (transpose epilogue) --------
__global__ __launch_bounds__(256) void k3_edge_final(const float* __restrict__ mm1pT,
                                                     const float* __restrict__ b01,
                                                     float* __restrict__ out1,
                                                     unsigned short* __restrict__ x1bf,
                                                     float* __restrict__ edge_card) {
  __shared__ float tile[32 * 260];
  __shared__ float d1s[32], css[32];
  const int tid = threadIdx.x;
  const int e0 = blockIdx.x * 32;
  float p[32];
#pragma unroll
  for (int u = 0; u < 32; ++u) p[u] = 0.f;
  for (int sp = 0; sp < MM1_SPLIT; ++sp) {
    const float4* rp = (const float4*)(mm1pT + ((size_t)sp * 272 + tid) * NE + e0);
#pragma unroll
    for (int u = 0; u < 8; ++u) {
      float4 v = rp[u];
      p[u * 4 + 0] += v.x; p[u * 4 + 1] += v.y; p[u * 4 + 2] += v.z; p[u * 4 + 3] += v.w;
    }
  }
  if (tid < 64) {
    int row = 256 + (tid >> 5), e = e0 + (tid & 31);
    float s = 0.f;
    for (int sp = 0; sp < MM1_SPLIT; ++sp) s += mm1pT[((size_t)sp * 272 + row) * NE + e];
    if (tid < 32) d1s[tid] = s; else css[tid & 31] = s;
  }
  __syncthreads();
  float bc = b01[tid];
#pragma unroll
  for (int u = 0; u < 32; ++u) tile[u * 260 + tid] = p[u] / d1s[u] + bc;
  if (tid < 32) {
    float cs = css[tid];
    edge_card[e0 + tid] = 1.0f / (cs * sqrtf(cs));
  }
  __syncthreads();
  const int e = tid >> 3, cb = (tid & 7) * 32;
  const float* trow = &tile[e * 260 + cb];
  float* orow = out1 + (size_t)(e0 + e) * CH + cb;
  unsigned short* xrow = x1bf + (size_t)(e0 + e) * CH + cb;
#pragma unroll
  for (int v = 0; v < 32; v += 4) {
    float4 x;
    x.x = trow[v]; x.y = trow[v + 1]; x.z = trow[v + 2]; x.w = trow[v + 3];
    float4 rl;
    rl.x = fmaxf(x.x, 0.f); rl.y = fmaxf(x.y, 0.f); rl.z = fmaxf(x.z, 0.f); rl.w = fmaxf(x.w, 0.f);
    *(float4*)&orow[v] = rl;
    ushort4 h;
    h.x = f2bf(x.x); h.y = f2bf(x.y); h.z = f2bf(x.z); h.w = f2bf(x.w);
    *(ushort4*)&xrow[v] = h;
  }
}

// ---------------- K5: y1 GEMM + scaled transpose epilogue ----------------
__global__ __launch_bounds__(256) void k5_y1(const unsigned short* __restrict__ x1bf,
                                             const unsigned short* __restrict__ W1T,
                                             const float* __restrict__ edge_card,
                                             unsigned short* __restrict__ y1sT) {
  __shared__ unsigned short a_lds[64 * 32];
  __shared__ unsigned short b_lds[256 * 32];
  const int tid = threadIdx.x;
  const int wave = tid >> 6, lane = tid & 63;
  const int quad = lane >> 4, l15 = lane & 15;
  const int m0 = blockIdx.x * 64;  // e-range

  f32x4 acc[4][4];
  const f32x4 fz = {0.f, 0.f, 0.f, 0.f};
#pragma unroll
  for (int i = 0; i < 4; ++i)
#pragma unroll
    for (int j = 0; j < 4; ++j) acc[i][j] = fz;

  for (int k0 = 0; k0 < CH; k0 += 32) {
    __syncthreads();
    {
      const unsigned short* g = x1bf + (size_t)(m0 + wave * 16 + (lane >> 2)) * CH + k0 + (lane & 3) * 8;
      async_copy16(g, &a_lds[(wave * 16) * 32]);
    }
#pragma unroll
    for (int i = 0; i < 4; ++i) {
      int rowbase = wave * 64 + i * 16;
      const unsigned short* g = W1T + (size_t)(rowbase + (lane >> 2)) * CH + k0 + (lane & 3) * 8;
      async_copy16(g, &b_lds[rowbase * 32]);
    }
    __syncthreads();
    bf16x8 af[4];
#pragma unroll
    for (int i = 0; i < 4; ++i)
      af[i] = *(const bf16x8*)&a_lds[(i * 16 + l15) * 32 + quad * 8];
#pragma unroll
    for (int j = 0; j < 4; ++j) {
      bf16x8 bfr = *(const bf16x8*)&b_lds[(wave * 64 + j * 16 + l15) * 32 + quad * 8];
#pragma unroll
      for (int i = 0; i < 4; ++i)
        acc[i][j] = __builtin_amdgcn_mfma_f32_16x16x32_bf16(af[i], bfr, acc[i][j], 0, 0, 0);
    }
  }
#pragma unroll
  for (int i = 0; i < 4; ++i) {
    int row4 = m0 + i * 16 + quad * 4;
    float4 ec = *(const float4*)(edge_card + row4);
#pragma unroll
    for (int j = 0; j < 4; ++j) {
      int col = wave * 64 + j * 16 + l15;
      f32x4 v = acc[i][j];
      ushort4 o;
      o.x = f2bf(v[0] * ec.x);
      o.y = f2bf(v[1] * ec.y);
      o.z = f2bf(v[2] * ec.z);
      o.w = f2bf(v[3] * ec.w);
      *(ushort4*)&y1sT[(size_t)col * NE + row4] = o;
    }
  }
}

// ---------------- K5b: y1sT aux rows ----------------
__global__ void k5b_aux(const float* __restrict__ edge_card, unsigned short* __restrict__ y1sT) {
  int e = blockIdx.x * 256 + threadIdx.x;
  y1sT[(size_t)256 * NE + e] = f2bf(edge_card[e]);
#pragma unroll
  for (int r = 257; r < 272; ++r) y1sT[(size_t)r * NE + e] = 0;
}

// ---------------- K6: reduce partials + finalize nodes (transpose epilogue) --------
__global__ __launch_bounds__(256) void k6_node_final(const float* __restrict__ mm2pT,
                                                     const float* __restrict__ b10,
                                                     float* __restrict__ out0) {
  __shared__ float tile[32 * 260];
  __shared__ float d0s[32];
  const int tid = threadIdx.x;
  const int n0 = blockIdx.x * 32;
  float p[32];
#pragma unroll
  for (int u = 0; u < 32; ++u) p[u] = 0.f;
  for (int sp = 0; sp < MM2_SPLIT; ++sp) {
    const float4* rp = (const float4*)(mm2pT + ((size_t)sp * 272 + tid) * NN + n0);
#pragma unroll
    for (int u = 0; u < 8; ++u) {
      float4 v = rp[u];
      p[u * 4 + 0] += v.x; p[u * 4 + 1] += v.y; p[u * 4 + 2] += v.z; p[u * 4 + 3] += v.w;
    }
  }
  if (tid < 32) {
    float s = 0.f;
    for (int sp = 0; sp < MM2_SPLIT; ++sp) s += mm2pT[((size_t)sp * 272 + 256) * NN + n0 + tid];
    d0s[tid] = s;
  }
  __syncthreads();
  float bc = b10[tid];
#pragma unroll
  for (int u = 0; u < 32; ++u) tile[u * 260 + tid] = p[u] / d0s[u] + bc;
  __syncthreads();
  const int n = tid >> 3, cb = (tid & 7) * 32;
  const float* trow = &tile[n * 260 + cb];
  float* orow = out0 + (size_t)(n0 + n) * CH + cb;
#pragma unroll
  for (int v = 0; v < 32; v += 4) {
    float4 x;
    x.x = trow[v]; x.y = trow[v + 1]; x.z = trow[v + 2]; x.w = trow[v + 3];
    float4 rl;
    rl.x = fmaxf(x.x, 0.f); rl.y = fmaxf(x.y, 0.f); rl.z = fmaxf(x.z, 0.f); rl.w = fmaxf(x.w, 0.f);
    *(float4*)&orow[v] = rl;
  }
}

extern "C" void kernel_launch(void* const* d_in, const int* in_sizes, int n_in,
                              void* d_out, int out_size, void* d_ws, size_t ws_size,
                              hipStream_t stream) {
  const float* x0 = (const float*)d_in[0];
  const float* B1 = (const float*)d_in[1];
  const float* W0 = (const float*)d_in[2];
  const float* W1 = (const float*)d_in[3];
  const float* b01 = (const float*)d_in[4];
  const float* b10 = (const float*)d_in[5];
  float* out0 = (float*)d_out;
  float* out1 = out0 + (size_t)NN * CH;

  char* ws = (char*)d_ws;
  size_t off = 0;
  auto take = [&](size_t bytes) {
    void* p = ws + off;
    off += (bytes + 255) & ~(size_t)255;
    return p;
  };
  unsigned short* b1h = (unsigned short*)take((size_t)NN * NE * 2);    // 268 MB [n][e]
  unsigned short* b1hT = (unsigned short*)take((size_t)NN * NE * 2);   // 268 MB [e][n]
  unsigned short* y0sT = (unsigned short*)take((size_t)272 * NN * 2);  // 8.9 MB
  unsigned short* y1sT = (unsigned short*)take((size_t)272 * NE * 2);  // 4.5 MB
  unsigned short* x1bf = (unsigned short*)take((size_t)NE * CH * 2);   // 4.2 MB
  float* mm1pT = (float*)take((size_t)MM1_SPLIT * 272 * NE * 4);       // 71.3 MB
  float* mm2pT = mm1pT;  // alias: mm1pT dead after K3; MM2_SPLIT*272*NN*4 same size
  float* node_card = (float*)take((size_t)NN * 4);
  float* edge_card = (float*)take((size_t)NE * 4);
  unsigned short* W0T = (unsigned short*)take((size_t)CH * CH * 2);
  unsigned short* W1T = (unsigned short*)take((size_t)CH * CH * 2);
  (void)ws_size; (void)in_sizes; (void)n_in; (void)out_size;

  k0_transpose_w<<<dim3(256, 2), 256, 0, stream>>>(W0, W1, W0T, W1T);
  k1_prep<<<NN / 64, 256, 0, stream>>>(B1, b1h, b1hT, node_card);
  k2_y0<<<NN / 64, 256, 0, stream>>>(x0, W0T, node_card, y0sT);
  k2b_aux<<<NN / 256, 256, 0, stream>>>(node_card, y0sT);
  mm1t_kernel<<<(NE / 64) * MM1_SPLIT, 256, 0, stream>>>(y0sT, b1hT, mm1pT);
  k3_edge_final<<<NE / 32, 256, 0, stream>>>(mm1pT, b01, out1, x1bf, edge_card);
  k5_y1<<<NE / 64, 256, 0, stream>>>(x1bf, W1T, edge_card, y1sT);
  k5b_aux<<<NE / 256, 256, 0, stream>>>(edge_card, y1sT);
  mm2t_kernel<<<(NN / 64) * MM2_SPLIT, 256, 0, stream>>>(y1sT, b1h, mm2pT);
  k6_node_final<<<NN / 32, 256, 0, stream>>>(mm2pT, b10, out0);
}

// Round 6
// 1148.450 us; speedup vs baseline: 1.2479x; 1.2479x over previous
//
// HNHN layer on MI355X (gfx950). Round 6:
//  - k1: tiled 128x128 transpose blocks (8192 blocks, bf16 LDS, rowsum atomics)
//  - MM cores: m-quarter blocks (64/64/64/80 rows) x N=128, BK=64, single barrier
//    per iter, dbuf async staging for BOTH operands, src-side chunk swizzle for
//    conflict-free ds_read_b128. 3 blocks/CU (52KB LDS), 12 waves/CU.
#include <hip/hip_runtime.h>
#include <stdint.h>

#define NN 16384
#define NE 8192
#define CH 256
#define MM1_SPLIT 8
#define MM2_SPLIT 4

typedef __attribute__((ext_vector_type(8))) short bf16x8;
typedef __attribute__((ext_vector_type(4))) float f32x4;

__device__ __forceinline__ unsigned short f2bf(float f) {  // RNE fp32->bf16
  unsigned u = __float_as_uint(f);
  u += 0x7FFFu + ((u >> 16) & 1u);
  return (unsigned short)(u >> 16);
}
__device__ __forceinline__ unsigned pack_trunc2(float a, float b) {  // exact for 0/1
  return (__float_as_uint(b) & 0xFFFF0000u) | (__float_as_uint(a) >> 16);
}
__device__ __forceinline__ void async_copy16(const void* gptr, void* lptr) {
  __builtin_amdgcn_global_load_lds((const __attribute__((address_space(1))) unsigned int*)gptr,
                                   (__attribute__((address_space(3))) unsigned int*)lptr,
                                   16, 0, 0);
}

// ---------------- K0: weight transpose to bf16 ----------------
__global__ void k0_transpose_w(const float* __restrict__ W0, const float* __restrict__ W1,
                               unsigned short* __restrict__ W0T, unsigned short* __restrict__ W1T) {
  const float* W = blockIdx.y ? W1 : W0;
  unsigned short* WT = blockIdx.y ? W1T : W0T;
  int n = blockIdx.x;
  int k = threadIdx.x;
  WT[n * CH + k] = f2bf(W[k * CH + n]);
}

// ---------------- K0z: zero rowsum accumulator ----------------
__global__ void k0z_zero(float* __restrict__ rowsum) {
  rowsum[blockIdx.x * 256 + threadIdx.x] = 0.f;
}

// ---------------- K1: 128x128 tile: b1h + b1hT + rowsum atomics ----------------
__global__ __launch_bounds__(256) void k1_prep(const float* __restrict__ B1,
                                               unsigned short* __restrict__ b1h,
                                               unsigned short* __restrict__ b1hT,
                                               float* __restrict__ rowsum) {
  __shared__ unsigned short t16[128 * 136];
  __shared__ float rs[128][9];
  const int tid = threadIdx.x;
  const int e0 = blockIdx.x * 128;
  const int n0 = blockIdx.y * 128;
  const int rr = tid >> 3;        // 0..31
  const int ec = (tid & 7) * 16;  // e-chunk base (floats)
  float part[4];
#pragma unroll
  for (int rg = 0; rg < 4; ++rg) {
    int r = rg * 32 + rr;
    const float* src = B1 + (size_t)(n0 + r) * NE + e0 + ec;
    float s = 0.f;
    unsigned w[8];
#pragma unroll
    for (int u = 0; u < 4; ++u) {
      float4 v = *(const float4*)(src + u * 4);
      s += v.x + v.y + v.z + v.w;
      w[u * 2] = pack_trunc2(v.x, v.y);
      w[u * 2 + 1] = pack_trunc2(v.z, v.w);
    }
    part[rg] = s;
    uint4* d = (uint4*)(b1h + (size_t)(n0 + r) * NE + e0 + ec);
    d[0] = make_uint4(w[0], w[1], w[2], w[3]);
    d[1] = make_uint4(w[4], w[5], w[6], w[7]);
    unsigned* lp = (unsigned*)&t16[r * 136 + ec];
#pragma unroll
    for (int u = 0; u < 8; ++u) lp[u] = w[u];
  }
#pragma unroll
  for (int rg = 0; rg < 4; ++rg) rs[rg * 32 + rr][tid & 7] = part[rg];
  __syncthreads();
  if (tid < 128) {
    float s = 0.f;
#pragma unroll
    for (int u = 0; u < 8; ++u) s += rs[tid][u];
    atomicAdd(rowsum + n0 + tid, s);
  }
  // phase 2: write b1hT. thread: e-pair p (64), n-quarter h (4: 32 n each)
  const int p = tid & 63, h = tid >> 6;
  unsigned lo[16], hi[16];
#pragma unroll
  for (int u = 0; u < 16; ++u) {
    int n = h * 32 + u * 2;
    unsigned a = *(const unsigned*)&t16[n * 136 + p * 2];
    unsigned b = *(const unsigned*)&t16[(n + 1) * 136 + p * 2];
    lo[u] = (a & 0xFFFFu) | (b << 16);
    hi[u] = (a >> 16) | (b & 0xFFFF0000u);
  }
  uint4* d0 = (uint4*)(b1hT + (size_t)(e0 + 2 * p) * NN + n0 + h * 32);
  d0[0] = make_uint4(lo[0], lo[1], lo[2], lo[3]);
  d0[1] = make_uint4(lo[4], lo[5], lo[6], lo[7]);
  d0[2] = make_uint4(lo[8], lo[9], lo[10], lo[11]);
  d0[3] = make_uint4(lo[12], lo[13], lo[14], lo[15]);
  uint4* d1 = (uint4*)(b1hT + (size_t)(e0 + 2 * p + 1) * NN + n0 + h * 32);
  d1[0] = make_uint4(hi[0], hi[1], hi[2], hi[3]);
  d1[1] = make_uint4(hi[4], hi[5], hi[6], hi[7]);
  d1[2] = make_uint4(hi[8], hi[9], hi[10], hi[11]);
  d1[3] = make_uint4(hi[12], hi[13], hi[14], hi[15]);
}

// ---------------- K1b: node_card ----------------
__global__ void k1b_nc(const float* __restrict__ rowsum, float* __restrict__ node_card) {
  int n = blockIdx.x * 256 + threadIdx.x;
  node_card[n] = rsqrtf(rowsum[n]);
}

// ---------------- K2: y0 GEMM + scaled transpose epilogue ----------------
__global__ __launch_bounds__(256) void k2_y0(const float* __restrict__ X0,
                                             const unsigned short* __restrict__ W0T,
                                             const float* __restrict__ node_card,
                                             unsigned short* __restrict__ y0sT) {
  __shared__ unsigned short a_lds[64 * 32];
  __shared__ unsigned short b_lds[256 * 32];
  const int tid = threadIdx.x;
  const int wave = tid >> 6, lane = tid & 63;
  const int quad = lane >> 4, l15 = lane & 15;
  const int m0 = blockIdx.x * 64;
  const int ar = tid >> 3, ac = (tid & 7) * 4;

  f32x4 acc[4][4];
  const f32x4 fz = {0.f, 0.f, 0.f, 0.f};
#pragma unroll
  for (int i = 0; i < 4; ++i)
#pragma unroll
    for (int j = 0; j < 4; ++j) acc[i][j] = fz;

  for (int k0 = 0; k0 < CH; k0 += 32) {
    __syncthreads();
#pragma unroll
    for (int p = 0; p < 2; ++p) {
      float4 v = *(const float4*)(X0 + (size_t)(m0 + ar + p * 32) * CH + k0 + ac);
      uint2 w;
      w.x = ((unsigned)f2bf(v.x)) | ((unsigned)f2bf(v.y) << 16);
      w.y = ((unsigned)f2bf(v.z)) | ((unsigned)f2bf(v.w) << 16);
      *(uint2*)&a_lds[(ar + p * 32) * 32 + ac] = w;
    }
#pragma unroll
    for (int i = 0; i < 4; ++i) {
      int rowbase = wave * 64 + i * 16;
      const unsigned short* g = W0T + (size_t)(rowbase + (lane >> 2)) * CH + k0 + (lane & 3) * 8;
      async_copy16(g, &b_lds[rowbase * 32]);
    }
    __syncthreads();
    bf16x8 af[4];
#pragma unroll
    for (int i = 0; i < 4; ++i)
      af[i] = *(const bf16x8*)&a_lds[(i * 16 + l15) * 32 + quad * 8];
#pragma unroll
    for (int j = 0; j < 4; ++j) {
      bf16x8 bfr = *(const bf16x8*)&b_lds[(wave * 64 + j * 16 + l15) * 32 + quad * 8];
#pragma unroll
      for (int i = 0; i < 4; ++i)
        acc[i][j] = __builtin_amdgcn_mfma_f32_16x16x32_bf16(af[i], bfr, acc[i][j], 0, 0, 0);
    }
  }
#pragma unroll
  for (int i = 0; i < 4; ++i) {
    int row4 = m0 + i * 16 + quad * 4;
    float4 nc = *(const float4*)(node_card + row4);
#pragma unroll
    for (int j = 0; j < 4; ++j) {
      int col = wave * 64 + j * 16 + l15;
      f32x4 v = acc[i][j];
      ushort4 o;
      o.x = f2bf(v[0] * nc.x);
      o.y = f2bf(v[1] * nc.y);
      o.z = f2bf(v[2] * nc.z);
      o.w = f2bf(v[3] * nc.w);
      *(ushort4*)&y0sT[(size_t)col * NN + row4] = o;
    }
  }
}

// ---------------- K2b: y0sT aux rows ----------------
__global__ void k2b_aux(const float* __restrict__ node_card, unsigned short* __restrict__ y0sT) {
  int n = blockIdx.x * 256 + threadIdx.x;
  y0sT[(size_t)256 * NN + n] = f2bf(node_card[n]);
  y0sT[(size_t)257 * NN + n] = 0x3F80;  // 1.0 bf16
#pragma unroll
  for (int r = 258; r < 272; ++r) y0sT[(size_t)r * NN + n] = 0;
}

// ------- MM core v3: outT[sp][272][NSZ] = Y(272 x K) @ Bm(NSZ x K) ---------------
// m-quarter per block (mq: 4/4/4/5 m-tiles), N=128, BK=64, splitK pinned to XCD.
// Single __syncthreads per iter; dbuf async staging for both operands issued
// immediately after the barrier (lead = one full compute phase).
// Source-side chunk swizzle: lane reads k-chunk ((l&3)-((l>>3)&3))&3 so frag
// ds_read_b128 at chunk (quad+((l15>>1)&3))&3 is 2-way bank-aliased (free).
template <int NSZ, int SPLIT>
__device__ __forceinline__ void mm_core(const unsigned short* __restrict__ Y,
                                        const unsigned short* __restrict__ Bm,
                                        float* __restrict__ outp) {
  constexpr int K = (NSZ == NE) ? NN : NE;
  constexpr int KS = K / SPLIT;
  constexpr int ITERS = KS / 64;
  __shared__ unsigned short a_lds[2][2][80][32];   // 20 KB
  __shared__ unsigned short b_lds[2][2][128][32];  // 32 KB
  const int tid = threadIdx.x;
  const int wave = tid >> 6, lane = tid & 63;
  const int quad = lane >> 4, l15 = lane & 15;
  const int bid = blockIdx.x;
  const int sp = bid % SPLIT;  // splitK slice -> XCD (round-robin dispatch)
  const int rest = bid / SPLIT;
  const int mq = rest & 3;
  const int nb = rest >> 2;
  const int n0 = nb * 128;
  const int mbase = mq * 64;
  const int MQ = (mq == 3) ? 5 : 4;
  const int kbase = sp * KS;
  const int lrow = lane >> 2;
  const int src_off = (((lane & 3) - ((lane >> 3) & 3)) & 3) * 8;  // shorts
  const int qpos = (quad + ((l15 >> 1) & 3)) & 3;

  f32x4 acc[5][2];
  const f32x4 fz = {0.f, 0.f, 0.f, 0.f};
#pragma unroll
  for (int m = 0; m < 5; ++m)
#pragma unroll
    for (int j = 0; j < 2; ++j) acc[m][j] = fz;

  auto stage = [&](int buf, int k0) {
    for (int g = wave; g < MQ; g += 4) {
#pragma unroll
      for (int kh = 0; kh < 2; ++kh) {
        const unsigned short* src =
            Y + (size_t)(mbase + g * 16 + lrow) * K + k0 + kh * 32 + src_off;
        async_copy16(src, &a_lds[buf][kh][g * 16][0]);
      }
    }
#pragma unroll
    for (int gg = 0; gg < 2; ++gg) {
      int g = wave * 2 + gg;
#pragma unroll
      for (int kh = 0; kh < 2; ++kh) {
        const unsigned short* src =
            Bm + (size_t)(n0 + g * 16 + lrow) * K + k0 + kh * 32 + src_off;
        async_copy16(src, &b_lds[buf][kh][g * 16][0]);
      }
    }
  };

  stage(0, kbase);
  for (int i = 0; i < ITERS; ++i) {
    __syncthreads();  // drains buf[i&1] asyncs (issued one compute phase ago)
    if (i + 1 < ITERS) stage((i + 1) & 1, kbase + (i + 1) * 64);
    const int buf = i & 1;
#pragma unroll
    for (int kh = 0; kh < 2; ++kh) {
      bf16x8 af[5], bfr[2];
#pragma unroll
      for (int m = 0; m < 5; ++m)
        if (m < MQ) af[m] = *(const bf16x8*)&a_lds[buf][kh][m * 16 + l15][qpos * 8];
#pragma unroll
      for (int j = 0; j < 2; ++j)
        bfr[j] = *(const bf16x8*)&b_lds[buf][kh][wave * 32 + j * 16 + l15][qpos * 8];
#pragma unroll
      for (int m = 0; m < 5; ++m)
        if (m < MQ)
#pragma unroll
          for (int j = 0; j < 2; ++j)
            acc[m][j] = __builtin_amdgcn_mfma_f32_16x16x32_bf16(af[m], bfr[j], acc[m][j], 0, 0, 0);
    }
  }
  float* op = outp + (size_t)sp * 272 * NSZ;
#pragma unroll
  for (int m = 0; m < 5; ++m) {
    if (m < MQ) {
      int c0 = mbase + m * 16 + quad * 4;
#pragma unroll
      for (int j = 0; j < 2; ++j) {
        int n = n0 + wave * 32 + j * 16 + l15;
#pragma unroll
        for (int r = 0; r < 4; ++r) op[(size_t)(c0 + r) * NSZ + n] = acc[m][j][r];
      }
    }
  }
}

__global__ __launch_bounds__(256) void mm1t_kernel(const unsigned short* __restrict__ y0sT,
                                                   const unsigned short* __restrict__ b1hT,
                                                   float* __restrict__ mm1pT) {
  mm_core<NE, MM1_SPLIT>(y0sT, b1hT, mm1pT);
}
__global__ __launch_bounds__(256) void mm2t_kernel(const unsigned short* __restrict__ y1sT,
                                                   const unsigned short* __restrict__ b1h,
                                                   float* __restrict__ mm2pT) {
  mm_core<NN, MM2_SPLIT>(y1sT, b1h, mm2pT);
}

// ---------------- K3: reduce partials + finalize edges (transpose epilogue) --------
__global__ __launch_bounds__(256) void k3_edge_final(const float* __restrict__ mm1pT,
                                                     const float* __restrict__ b01,
                                                     float* __restrict__ out1,
                                                     unsigned short* __restrict__ x1bf,
                                                     float* __restrict__ edge_card) {
  __shared__ float tile[32 * 260];
  __shared__ float d1s[32], css[32];
  const int tid = threadIdx.x;
  const int e0 = blockIdx.x * 32;
  float p[32];
#pragma unroll
  for (int u = 0; u < 32; ++u) p[u] = 0.f;
  for (int sp = 0; sp < MM1_SPLIT; ++sp) {
    const float4* rp = (const float4*)(mm1pT + ((size_t)sp * 272 + tid) * NE + e0);
#pragma unroll
    for (int u = 0; u < 8; ++u) {
      float4 v = rp[u];
      p[u * 4 + 0] += v.x; p[u * 4 + 1] += v.y; p[u * 4 + 2] += v.z; p[u * 4 + 3] += v.w;
    }
  }
  if (tid < 64) {
    int row = 256 + (tid >> 5), e = e0 + (tid & 31);
    float s = 0.f;
    for (int sp = 0; sp < MM1_SPLIT; ++sp) s += mm1pT[((size_t)sp * 272 + row) * NE + e];
    if (tid < 32) d1s[tid] = s; else css[tid & 31] = s;
  }
  __syncthreads();
  float bc = b01[tid];
#pragma unroll
  for (int u = 0; u < 32; ++u) tile[u * 260 + tid] = p[u] / d1s[u] + bc;
  if (tid < 32) {
    float cs = css[tid];
    edge_card[e0 + tid] = 1.0f / (cs * sqrtf(cs));
  }
  __syncthreads();
  const int e = tid >> 3, cb = (tid & 7) * 32;
  const float* trow = &tile[e * 260 + cb];
  float* orow = out1 + (size_t)(e0 + e) * CH + cb;
  unsigned short* xrow = x1bf + (size_t)(e0 + e) * CH + cb;
#pragma unroll
  for (int v = 0; v < 32; v += 4) {
    float4 x;
    x.x = trow[v]; x.y = trow[v + 1]; x.z = trow[v + 2]; x.w = trow[v + 3];
    float4 rl;
    rl.x = fmaxf(x.x, 0.f); rl.y = fmaxf(x.y, 0.f); rl.z = fmaxf(x.z, 0.f); rl.w = fmaxf(x.w, 0.f);
    *(float4*)&orow[v] = rl;
    ushort4 h;
    h.x = f2bf(x.x); h.y = f2bf(x.y); h.z = f2bf(x.z); h.w = f2bf(x.w);
    *(ushort4*)&xrow[v] = h;
  }
}

// ---------------- K5: y1 GEMM + scaled transpose epilogue ----------------
__global__ __launch_bounds__(256) void k5_y1(const unsigned short* __restrict__ x1bf,
                                             const unsigned short* __restrict__ W1T,
                                             const float* __restrict__ edge_card,
                                             unsigned short* __restrict__ y1sT) {
  __shared__ unsigned short a_lds[64 * 32];
  __shared__ unsigned short b_lds[256 * 32];
  const int tid = threadIdx.x;
  const int wave = tid >> 6, lane = tid & 63;
  const int quad = lane >> 4, l15 = lane & 15;
  const int m0 = blockIdx.x * 64;  // e-range

  f32x4 acc[4][4];
  const f32x4 fz = {0.f, 0.f, 0.f, 0.f};
#pragma unroll
  for (int i = 0; i < 4; ++i)
#pragma unroll
    for (int j = 0; j < 4; ++j) acc[i][j] = fz;

  for (int k0 = 0; k0 < CH; k0 += 32) {
    __syncthreads();
    {
      const unsigned short* g = x1bf + (size_t)(m0 + wave * 16 + (lane >> 2)) * CH + k0 + (lane & 3) * 8;
      async_copy16(g, &a_lds[(wave * 16) * 32]);
    }
#pragma unroll
    for (int i = 0; i < 4; ++i) {
      int rowbase = wave * 64 + i * 16;
      const unsigned short* g = W1T + (size_t)(rowbase + (lane >> 2)) * CH + k0 + (lane & 3) * 8;
      async_copy16(g, &b_lds[rowbase * 32]);
    }
    __syncthreads();
    bf16x8 af[4];
#pragma unroll
    for (int i = 0; i < 4; ++i)
      af[i] = *(const bf16x8*)&a_lds[(i * 16 + l15) * 32 + quad * 8];
#pragma unroll
    for (int j = 0; j < 4; ++j) {
      bf16x8 bfr = *(const bf16x8*)&b_lds[(wave * 64 + j * 16 + l15) * 32 + quad * 8];
#pragma unroll
      for (int i = 0; i < 4; ++i)
        acc[i][j] = __builtin_amdgcn_mfma_f32_16x16x32_bf16(af[i], bfr, acc[i][j], 0, 0, 0);
    }
  }
#pragma unroll
  for (int i = 0; i < 4; ++i) {
    int row4 = m0 + i * 16 + quad * 4;
    float4 ec = *(const float4*)(edge_card + row4);
#pragma unroll
    for (int j = 0; j < 4; ++j) {
      int col = wave * 64 + j * 16 + l15;
      f32x4 v = acc[i][j];
      ushort4 o;
      o.x = f2bf(v[0] * ec.x);
      o.y = f2bf(v[1] * ec.y);
      o.z = f2bf(v[2] * ec.z);
      o.w = f2bf(v[3] * ec.w);
      *(ushort4*)&y1sT[(size_t)col * NE + row4] = o;
    }
  }
}

// ---------------- K5b: y1sT aux rows ----------------
__global__ void k5b_aux(const float* __restrict__ edge_card, unsigned short* __restrict__ y1sT) {
  int e = blockIdx.x * 256 + threadIdx.x;
  y1sT[(size_t)256 * NE + e] = f2bf(edge_card[e]);
#pragma unroll
  for (int r = 257; r < 272; ++r) y1sT[(size_t)r * NE + e] = 0;
}

// ---------------- K6: reduce partials + finalize nodes (transpose epilogue) --------
__global__ __launch_bounds__(256) void k6_node_final(const float* __restrict__ mm2pT,
                                                     const float* __restrict__ b10,
                                                     float* __restrict__ out0) {
  __shared__ float tile[32 * 260];
  __shared__ float d0s[32];
  const int tid = threadIdx.x;
  const int n0 = blockIdx.x * 32;
  float p[32];
#pragma unroll
  for (int u = 0; u < 32; ++u) p[u] = 0.f;
  for (int sp = 0; sp < MM2_SPLIT; ++sp) {
    const float4* rp = (const float4*)(mm2pT + ((size_t)sp * 272 + tid) * NN + n0);
#pragma unroll
    for (int u = 0; u < 8; ++u) {
      float4 v = rp[u];
      p[u * 4 + 0] += v.x; p[u * 4 + 1] += v.y; p[u * 4 + 2] += v.z; p[u * 4 + 3] += v.w;
    }
  }
  if (tid < 32) {
    float s = 0.f;
    for (int sp = 0; sp < MM2_SPLIT; ++sp) s += mm2pT[((size_t)sp * 272 + 256) * NN + n0 + tid];
    d0s[tid] = s;
  }
  __syncthreads();
  float bc = b10[tid];
#pragma unroll
  for (int u = 0; u < 32; ++u) tile[u * 260 + tid] = p[u] / d0s[u] + bc;
  __syncthreads();
  const int n = tid >> 3, cb = (tid & 7) * 32;
  const float* trow = &tile[n * 260 + cb];
  float* orow = out0 + (size_t)(n0 + n) * CH + cb;
#pragma unroll
  for (int v = 0; v < 32; v += 4) {
    float4 x;
    x.x = trow[v]; x.y = trow[v + 1]; x.z = trow[v + 2]; x.w = trow[v + 3];
    float4 rl;
    rl.x = fmaxf(x.x, 0.f); rl.y = fmaxf(x.y, 0.f); rl.z = fmaxf(x.z, 0.f); rl.w = fmaxf(x.w, 0.f);
    *(float4*)&orow[v] = rl;
  }
}

extern "C" void kernel_launch(void* const* d_in, const int* in_sizes, int n_in,
                              void* d_out, int out_size, void* d_ws, size_t ws_size,
                              hipStream_t stream) {
  const float* x0 = (const float*)d_in[0];
  const float* B1 = (const float*)d_in[1];
  const float* W0 = (const float*)d_in[2];
  const float* W1 = (const float*)d_in[3];
  const float* b01 = (const float*)d_in[4];
  const float* b10 = (const float*)d_in[5];
  float* out0 = (float*)d_out;
  float* out1 = out0 + (size_t)NN * CH;

  char* ws = (char*)d_ws;
  size_t off = 0;
  auto take = [&](size_t bytes) {
    void* p = ws + off;
    off += (bytes + 255) & ~(size_t)255;
    return p;
  };
  unsigned short* b1h = (unsigned short*)take((size_t)NN * NE * 2);    // 268 MB [n][e]
  unsigned short* b1hT = (unsigned short*)take((size_t)NN * NE * 2);   // 268 MB [e][n]
  unsigned short* y0sT = (unsigned short*)take((size_t)272 * NN * 2);  // 8.9 MB
  unsigned short* y1sT = (unsigned short*)take((size_t)272 * NE * 2);  // 4.5 MB
  unsigned short* x1bf = (unsigned short*)take((size_t)NE * CH * 2);   // 4.2 MB
  float* mm1pT = (float*)take((size_t)MM1_SPLIT * 272 * NE * 4);       // 71.3 MB
  float* mm2pT = mm1pT;  // alias: mm1pT dead after K3; same byte size
  float* rowsum = (float*)take((size_t)NN * 4);
  float* node_card = (float*)take((size_t)NN * 4);
  float* edge_card = (float*)take((size_t)NE * 4);
  unsigned short* W0T = (unsigned short*)take((size_t)CH * CH * 2);
  unsigned short* W1T = (unsigned short*)take((size_t)CH * CH * 2);
  (void)ws_size; (void)in_sizes; (void)n_in; (void)out_size;

  k0_transpose_w<<<dim3(256, 2), 256, 0, stream>>>(W0, W1, W0T, W1T);
  k0z_zero<<<NN / 256, 256, 0, stream>>>(rowsum);
  k1_prep<<<dim3(NE / 128, NN / 128), 256, 0, stream>>>(B1, b1h, b1hT, rowsum);
  k1b_nc<<<NN / 256, 256, 0, stream>>>(rowsum, node_card);
  k2_y0<<<NN / 64, 256, 0, stream>>>(x0, W0T, node_card, y0sT);
  k2b_aux<<<NN / 256, 256, 0, stream>>>(node_card, y0sT);
  mm1t_kernel<<<(NE / 128) * 4 * MM1_SPLIT, 256, 0, stream>>>(y0sT, b1hT, mm1pT);
  k3_edge_final<<<NE / 32, 256, 0, stream>>>(mm1pT, b01, out1, x1bf, edge_card);
  k5_y1<<<NE / 64, 256, 0, stream>>>(x1bf, W1T, edge_card, y1sT);
  k5b_aux<<<NE / 256, 256, 0, stream>>>(edge_card, y1sT);
  mm2t_kernel<<<(NN / 128) * 4 * MM2_SPLIT, 256, 0, stream>>>(y1sT, b1h, mm2pT);
  k6_node_final<<<NN / 32, 256, 0, stream>>>(mm2pT, b10, out0);
}